// Round 7
// baseline (612.195 us; speedup 1.0000x reference)
//
#include <hip/hip_runtime.h>

#define N_NODES 50000
#define N_EDGES 800000
#define IN_CH   64
#define OUT_CH  128
#define FEAT    192   // IN_CH * 3 powers
#define NB      ((N_NODES + 255) / 256)   // 196 node-blocks / buckets
#define N_TILES (N_NODES / 16)            // 3125 wave-tiles for GEMM

typedef __attribute__((ext_vector_type(8))) short short8;  // 8 bf16 (4 VGPRs)
typedef __attribute__((ext_vector_type(4))) float f32x4;

static __device__ __forceinline__ unsigned short f2bf(float f) {
  // round-to-nearest-even f32 -> bf16 (finite inputs)
  unsigned int u = __float_as_uint(f);
  u += 0x7FFFu + ((u >> 16) & 1u);
  return (unsigned short)(u >> 16);
}
static __device__ __forceinline__ float bf2f(unsigned int s) {
  return __uint_as_float(s << 16);
}

// ---------------------------------------------------------------------------
// CSR step A: 196-bucket histogram of dst>>8. LDS-aggregated; ~196 global
// atomics per block (512 grid-stride blocks -> ~100k global atomics).
// ---------------------------------------------------------------------------
__global__ __launch_bounds__(256) void bucket_hist_kernel(
    const int* __restrict__ ei, int* __restrict__ bcount) {
  __shared__ int lh[NB];
  for (int i = threadIdx.x; i < NB; i += 256) lh[i] = 0;
  __syncthreads();
  for (int e = blockIdx.x * 256 + threadIdx.x; e < N_EDGES;
       e += gridDim.x * 256)
    atomicAdd(&lh[((unsigned)ei[N_EDGES + e]) >> 8], 1);
  __syncthreads();
  for (int i = threadIdx.x; i < NB; i += 256) {
    const int c = lh[i];
    if (c) atomicAdd(&bcount[i], c);
  }
}

// ---------------------------------------------------------------------------
// CSR step B: exclusive scan of the 196 bucket counts (single block).
// Emits boffset[0..NB] and initializes bcursor. rowptr[N_NODES] is constant.
// ---------------------------------------------------------------------------
__global__ __launch_bounds__(256) void bucket_scan_kernel(
    const int* __restrict__ bcount, int* __restrict__ boffset,
    int* __restrict__ bcursor, int* __restrict__ rowptr) {
  __shared__ int s[256];
  const int tid = threadIdx.x;
  const int v = (tid < NB) ? bcount[tid] : 0;
  s[tid] = v;
  __syncthreads();
  for (int off = 1; off < 256; off <<= 1) {
    const int t = (tid >= off) ? s[tid - off] : 0;
    __syncthreads();
    s[tid] += t;
    __syncthreads();
  }
  if (tid < NB) {
    const int ex = s[tid] - v;
    boffset[tid] = ex;
    bcursor[tid] = ex;
  }
  if (tid == 0) {
    boffset[NB] = N_EDGES;
    rowptr[N_NODES] = N_EDGES;
  }
}

// ---------------------------------------------------------------------------
// CSR step C: append each edge into its dst-bucket as a packed word
// (src<<8)|(dst&255). src < 2^17 so it fits. Writes cluster at each
// bucket's advancing cursor frontier -> full-line utilization in L2.
// ---------------------------------------------------------------------------
__global__ __launch_bounds__(256) void bucket_fill_kernel(
    const int* __restrict__ ei, int* __restrict__ bcursor,
    unsigned* __restrict__ pairs) {
  const int e = blockIdx.x * 256 + threadIdx.x;
  if (e >= N_EDGES) return;
  const unsigned s = (unsigned)ei[e];
  const unsigned d = (unsigned)ei[N_EDGES + e];
  const int pos = atomicAdd(&bcursor[d >> 8], 1);
  pairs[pos] = (s << 8) | (d & 255u);
}

// ---------------------------------------------------------------------------
// CSR step D: per-bucket local CSR. One block per bucket: LDS histogram of
// the 256 local nodes, LDS scan, then scatter srcs into the bucket's
// contiguous global region. All random writes confined to ~16 KB.
// ---------------------------------------------------------------------------
__global__ __launch_bounds__(256) void bucket_csr_kernel(
    const unsigned* __restrict__ pairs, const int* __restrict__ boffset,
    int* __restrict__ rowptr, int* __restrict__ srcs) {
  __shared__ int cnt[256];
  __shared__ int sc[256];
  const int tid = threadIdx.x;
  const int base = boffset[blockIdx.x];
  const int limit = boffset[blockIdx.x + 1];

  cnt[tid] = 0;
  __syncthreads();
  for (int i = base + tid; i < limit; i += 256)
    atomicAdd(&cnt[pairs[i] & 255u], 1);
  __syncthreads();

  const int v = cnt[tid];
  sc[tid] = v;
  __syncthreads();
  for (int off = 1; off < 256; off <<= 1) {
    const int t = (tid >= off) ? sc[tid - off] : 0;
    __syncthreads();
    sc[tid] += t;
    __syncthreads();
  }
  const int ex = base + sc[tid] - v;  // exclusive global position

  const int node = blockIdx.x * 256 + tid;
  if (node < N_NODES) rowptr[node] = ex;

  cnt[tid] = ex;  // reuse as cursor
  __syncthreads();
  for (int i = base + tid; i < limit; i += 256) {
    const unsigned p = pairs[i];
    const int pos = atomicAdd(&cnt[p & 255u], 1);
    srcs[pos] = (int)(p >> 8);
  }
}

// ---------------------------------------------------------------------------
// Cast x (f32) -> xb (bf16). 8 elems/thread.
// ---------------------------------------------------------------------------
__global__ __launch_bounds__(256) void cast_x_kernel(
    const float* __restrict__ x, unsigned short* __restrict__ xb) {
  const int t = blockIdx.x * blockDim.x + threadIdx.x;
  if (t >= (N_NODES * IN_CH) / 8) return;
  const float4 a = reinterpret_cast<const float4*>(x)[t * 2];
  const float4 c = reinterpret_cast<const float4*>(x)[t * 2 + 1];
  union { unsigned int u[4]; uint4 v; } o;
  o.u[0] = (unsigned)f2bf(a.x) | ((unsigned)f2bf(a.y) << 16);
  o.u[1] = (unsigned)f2bf(a.z) | ((unsigned)f2bf(a.w) << 16);
  o.u[2] = (unsigned)f2bf(c.x) | ((unsigned)f2bf(c.y) << 16);
  o.u[3] = (unsigned)f2bf(c.z) | ((unsigned)f2bf(c.w) << 16);
  reinterpret_cast<uint4*>(xb)[t] = o.v;
}

// ---------------------------------------------------------------------------
// W [OUT_CH, FEAT] f32 -> Wf bf16 in MFMA-fragment order:
// Wf[((kk*8+nt)*64 + lane)*8 + j] = W[nt*16+(lane&15)][kk*32+(lane>>4)*8+j]
// ---------------------------------------------------------------------------
__global__ __launch_bounds__(256) void wfrag_kernel(
    const float* __restrict__ W, unsigned short* __restrict__ Wf) {
  const int t = blockIdx.x * blockDim.x + threadIdx.x;
  if (t >= 6 * 8 * 64 * 8) return;  // 24576 == FEAT*OUT_CH
  const int j = t & 7;
  const int l = (t >> 3) & 63;
  const int nt = (t >> 9) & 7;
  const int kk = t >> 12;
  const int o = nt * 16 + (l & 15);
  const int k = kk * 32 + (l >> 4) * 8 + j;
  Wf[t] = f2bf(W[o * FEAT + k]);
}

// ---------------------------------------------------------------------------
// Gather hop (bf16): hout[n][c] = sum over in-edges(n) of hin[src][c].
// One wave per node; g=lane>>3 picks edge slot (8 in flight), s=lane&7
// picks the 8-channel slice (uint4 = 16B). f32 accumulate, shfl_xor combine.
// ---------------------------------------------------------------------------
__global__ __launch_bounds__(256) void gather_kernel(
    const unsigned short* __restrict__ hin, const int* __restrict__ rowptr,
    const int* __restrict__ srcs, unsigned short* __restrict__ hout) {
  const int gid = blockIdx.x * blockDim.x + threadIdx.x;
  const int node = gid >> 6;
  if (node >= N_NODES) return;
  const int lane = threadIdx.x & 63;
  const int g = lane >> 3;
  const int s = lane & 7;

  const int beg = rowptr[node];
  const int end = rowptr[node + 1];

  float acc[8];
#pragma unroll
  for (int j = 0; j < 8; ++j) acc[j] = 0.0f;

  for (int i = beg + g; i < end; i += 8) {
    const int src = srcs[i];
    const uint4 v = *reinterpret_cast<const uint4*>(
        hin + (size_t)src * IN_CH + s * 8);
    acc[0] += bf2f(v.x & 0xffffu); acc[1] += bf2f(v.x >> 16);
    acc[2] += bf2f(v.y & 0xffffu); acc[3] += bf2f(v.y >> 16);
    acc[4] += bf2f(v.z & 0xffffu); acc[5] += bf2f(v.z >> 16);
    acc[6] += bf2f(v.w & 0xffffu); acc[7] += bf2f(v.w >> 16);
  }

#pragma unroll
  for (int j = 0; j < 8; ++j) {
    acc[j] += __shfl_xor(acc[j], 8);
    acc[j] += __shfl_xor(acc[j], 16);
    acc[j] += __shfl_xor(acc[j], 32);
  }

  if (g == 0) {
    union { unsigned int u[4]; uint4 v; } o;
    o.u[0] = (unsigned)f2bf(acc[0]) | ((unsigned)f2bf(acc[1]) << 16);
    o.u[1] = (unsigned)f2bf(acc[2]) | ((unsigned)f2bf(acc[3]) << 16);
    o.u[2] = (unsigned)f2bf(acc[4]) | ((unsigned)f2bf(acc[5]) << 16);
    o.u[3] = (unsigned)f2bf(acc[6]) | ((unsigned)f2bf(acc[7]) << 16);
    *reinterpret_cast<uint4*>(hout + (size_t)node * IN_CH + s * 8) = o.v;
  }
}

// ---------------------------------------------------------------------------
// MFMA GEMM: out[n,o] = b[o] + [xb|h1b|h2b][n,:] @ W[o,:]  (bf16 in, f32 acc)
// One wave per 16-node tile; 8 n-tiles of 16 out-ch; K = 6 chunks of 32.
// C/D (m89-verified): D[(l>>4)*4+r][l&15].
// ---------------------------------------------------------------------------
__global__ __launch_bounds__(256) void gemm_kernel(
    const unsigned short* __restrict__ xb,
    const unsigned short* __restrict__ h1b,
    const unsigned short* __restrict__ h2b,
    const unsigned short* __restrict__ Wf, const float* __restrict__ b,
    float* __restrict__ out) {
  const int wave = (blockIdx.x * 256 + threadIdx.x) >> 6;
  if (wave >= N_TILES) return;
  const int lane = threadIdx.x & 63;
  const int node0 = wave * 16;
  const int mrow = lane & 15;
  const int kg = lane >> 4;

  f32x4 acc[8];
#pragma unroll
  for (int nt = 0; nt < 8; ++nt) acc[nt] = (f32x4){0.f, 0.f, 0.f, 0.f};

  const unsigned short* const srcarr[3] = {xb, h1b, h2b};
#pragma unroll
  for (int kk = 0; kk < 6; ++kk) {
    const unsigned short* a = srcarr[kk >> 1];
    const short8 af = *reinterpret_cast<const short8*>(
        a + (size_t)(node0 + mrow) * IN_CH + (kk & 1) * 32 + kg * 8);
#pragma unroll
    for (int nt = 0; nt < 8; ++nt) {
      const short8 bf = *reinterpret_cast<const short8*>(
          Wf + ((size_t)(kk * 8 + nt) * 64 + lane) * 8);
      acc[nt] = __builtin_amdgcn_mfma_f32_16x16x32_bf16(af, bf, acc[nt], 0, 0, 0);
    }
  }

#pragma unroll
  for (int nt = 0; nt < 8; ++nt) {
    const int oc = nt * 16 + mrow;
    const float bias = b[oc];
#pragma unroll
    for (int r = 0; r < 4; ++r) {
      out[(size_t)(node0 + kg * 4 + r) * OUT_CH + oc] = acc[nt][r] + bias;
    }
  }
}

extern "C" void kernel_launch(void* const* d_in, const int* in_sizes, int n_in,
                              void* d_out, int out_size, void* d_ws,
                              size_t ws_size, hipStream_t stream) {
  const float* x = (const float*)d_in[0];
  const int* ei = (const int*)d_in[1];   // [2, N_EDGES], int32 per harness
  const float* W = (const float*)d_in[2];
  const float* b = (const float*)d_in[3];
  float* out = (float*)d_out;

  // Workspace layout (bytes):
  //   xb | h1b | h2b (pairs aliases h2b — dead until gather hop 2) |
  //   Wf | bcount | boffset | bcursor | rowptr | srcs         (~22.7 MB)
  char* p = (char*)d_ws;
  unsigned short* xb = (unsigned short*)p;  p += (size_t)N_NODES * IN_CH * 2;
  unsigned short* h1b = (unsigned short*)p; p += (size_t)N_NODES * IN_CH * 2;
  unsigned short* h2b = (unsigned short*)p;
  unsigned* pairs = (unsigned*)h2b;         p += (size_t)N_NODES * IN_CH * 2;
  unsigned short* Wf = (unsigned short*)p;  p += (size_t)FEAT * OUT_CH * 2;
  int* bcount = (int*)p;  p += (size_t)NB * 4;
  int* boffset = (int*)p; p += (size_t)(NB + 1) * 4;
  int* bcursor = (int*)p; p += (size_t)NB * 4;
  int* rowptr = (int*)p;  p += (size_t)(N_NODES + 1) * 4;
  int* srcs = (int*)p;

  // Zero only the 196 bucket counters (ws poisoned to 0xAA before every call).
  hipMemsetAsync(bcount, 0, NB * sizeof(int), stream);

  const int eblocks = (N_EDGES + 255) / 256;

  // Bucketed CSR build.
  bucket_hist_kernel<<<512, 256, 0, stream>>>(ei, bcount);
  bucket_scan_kernel<<<1, 256, 0, stream>>>(bcount, boffset, bcursor, rowptr);
  bucket_fill_kernel<<<eblocks, 256, 0, stream>>>(ei, bcursor, pairs);
  bucket_csr_kernel<<<NB, 256, 0, stream>>>(pairs, boffset, rowptr, srcs);

  // bf16 casts / weight fragment shuffle.
  cast_x_kernel<<<(N_NODES * IN_CH / 8 + 255) / 256, 256, 0, stream>>>(x, xb);
  wfrag_kernel<<<(FEAT * OUT_CH + 255) / 256, 256, 0, stream>>>(W, Wf);

  // Hop 1: h1 = gather(xb); Hop 2: h2 = gather(h1b) (overwrites pairs, OK).
  const int gblocks = (N_NODES * 64 + 255) / 256;
  gather_kernel<<<gblocks, 256, 0, stream>>>(xb, rowptr, srcs, h1b);
  gather_kernel<<<gblocks, 256, 0, stream>>>(h1b, rowptr, srcs, h2b);

  // out = [xb|h1b|h2b] @ W.T + b via MFMA.
  const int gemmblocks = (N_TILES + 3) / 4;  // 4 waves per block
  gemm_kernel<<<gemmblocks, 256, 0, stream>>>(xb, h1b, h2b, Wf, b, out);
}

// Round 8
// 164.371 us; speedup vs baseline: 3.7245x; 3.7245x over previous
//
#include <hip/hip_runtime.h>

#define N_NODES 50000
#define N_EDGES 800000
#define IN_CH   64
#define OUT_CH  128
#define FEAT    192   // IN_CH * 3 powers
#define NB      ((N_NODES + 255) / 256)   // 196 dst-buckets of 256 nodes
#define EPB     1024                      // edges per partition block
#define NPB     ((N_EDGES + EPB - 1) / EPB)  // 782 edge-blocks
#define JPT     ((NPB + 255) / 256)       // 4 edge-blocks per scan thread
#define N_TILES (N_NODES / 16)            // 3125 wave-tiles for GEMM

typedef __attribute__((ext_vector_type(8))) short short8;  // 8 bf16 (4 VGPRs)
typedef __attribute__((ext_vector_type(4))) float f32x4;

static __device__ __forceinline__ unsigned short f2bf(float f) {
  unsigned int u = __float_as_uint(f);
  u += 0x7FFFu + ((u >> 16) & 1u);
  return (unsigned short)(u >> 16);
}
static __device__ __forceinline__ float bf2f(unsigned int s) {
  return __uint_as_float(s << 16);
}

// ---------------------------------------------------------------------------
// P1: per-edge-block histogram over the 196 dst buckets. LDS atomics only;
// coalesced row write hist[b][k].
// ---------------------------------------------------------------------------
__global__ __launch_bounds__(256) void part_hist_kernel(
    const int* __restrict__ ei, int* __restrict__ hist) {
  __shared__ int lh[NB];
  const int b = blockIdx.x;
  for (int i = threadIdx.x; i < NB; i += 256) lh[i] = 0;
  __syncthreads();
  const int e0 = b * EPB;
  const int e1 = (e0 + EPB < N_EDGES) ? e0 + EPB : N_EDGES;
  for (int e = e0 + threadIdx.x; e < e1; e += 256)
    atomicAdd(&lh[((unsigned)ei[N_EDGES + e]) >> 8], 1);
  __syncthreads();
  for (int i = threadIdx.x; i < NB; i += 256) hist[b * NB + i] = lh[i];
}

// ---------------------------------------------------------------------------
// P2a: per-bucket exclusive scan across the 782 edge-blocks.
// Block k: offs_t[k][j] = sum_{j'<j} hist[j'][k]; total[k] = full sum.
// ---------------------------------------------------------------------------
__global__ __launch_bounds__(256) void part_scan_kernel(
    const int* __restrict__ hist, int* __restrict__ offs_t,
    int* __restrict__ total) {
  __shared__ int part[256];
  const int k = blockIdx.x;
  const int t = threadIdx.x;
  int loc[JPT];
  int sum = 0;
#pragma unroll
  for (int u = 0; u < JPT; ++u) {
    const int j = t * JPT + u;
    const int v = (j < NPB) ? hist[j * NB + k] : 0;
    loc[u] = v;
    sum += v;
  }
  part[t] = sum;
  __syncthreads();
  for (int off = 1; off < 256; off <<= 1) {
    const int v = (t >= off) ? part[t - off] : 0;
    __syncthreads();
    part[t] += v;
    __syncthreads();
  }
  int run = part[t] - sum;
#pragma unroll
  for (int u = 0; u < JPT; ++u) {
    const int j = t * JPT + u;
    if (j < NPB) offs_t[k * NPB + j] = run;
    run += loc[u];
  }
  if (t == 255) total[k] = part[255];
}

// ---------------------------------------------------------------------------
// P2b: exclusive scan of the 196 bucket totals -> boffset[0..NB].
// ---------------------------------------------------------------------------
__global__ __launch_bounds__(256) void part_scan2_kernel(
    const int* __restrict__ total, int* __restrict__ boffset,
    int* __restrict__ rowptr) {
  __shared__ int s[256];
  const int tid = threadIdx.x;
  const int v = (tid < NB) ? total[tid] : 0;
  s[tid] = v;
  __syncthreads();
  for (int off = 1; off < 256; off <<= 1) {
    const int t = (tid >= off) ? s[tid - off] : 0;
    __syncthreads();
    s[tid] += t;
    __syncthreads();
  }
  if (tid < NB) boffset[tid] = s[tid] - v;
  if (tid == 0) {
    boffset[NB] = N_EDGES;
    rowptr[N_NODES] = N_EDGES;
  }
}

// ---------------------------------------------------------------------------
// P3: deterministic fill. Each edge-block writes its edges to precomputed
// per-bucket bases; only LDS atomics for intra-block rank. Packed word:
// (src<<8)|(dst&255) (src < 2^17).
// ---------------------------------------------------------------------------
__global__ __launch_bounds__(256) void part_fill_kernel(
    const int* __restrict__ ei, const int* __restrict__ boffset,
    const int* __restrict__ offs_t, unsigned* __restrict__ pairs) {
  __shared__ int cur[NB];
  const int b = blockIdx.x;
  for (int k = threadIdx.x; k < NB; k += 256)
    cur[k] = boffset[k] + offs_t[k * NPB + b];
  __syncthreads();
  const int e0 = b * EPB;
  const int e1 = (e0 + EPB < N_EDGES) ? e0 + EPB : N_EDGES;
  for (int e = e0 + threadIdx.x; e < e1; e += 256) {
    const unsigned s = (unsigned)ei[e];
    const unsigned d = (unsigned)ei[N_EDGES + e];
    const int pos = atomicAdd(&cur[d >> 8], 1);
    pairs[pos] = (s << 8) | (d & 255u);
  }
}

// ---------------------------------------------------------------------------
// P4: per-bucket local CSR. One block per bucket: LDS hist of the 256 local
// nodes, LDS scan, scatter srcs into the bucket's contiguous region.
// ---------------------------------------------------------------------------
__global__ __launch_bounds__(256) void bucket_csr_kernel(
    const unsigned* __restrict__ pairs, const int* __restrict__ boffset,
    int* __restrict__ rowptr, int* __restrict__ srcs) {
  __shared__ int cnt[256];
  __shared__ int sc[256];
  const int tid = threadIdx.x;
  const int base = boffset[blockIdx.x];
  const int limit = boffset[blockIdx.x + 1];

  cnt[tid] = 0;
  __syncthreads();
  for (int i = base + tid; i < limit; i += 256)
    atomicAdd(&cnt[pairs[i] & 255u], 1);
  __syncthreads();

  const int v = cnt[tid];
  sc[tid] = v;
  __syncthreads();
  for (int off = 1; off < 256; off <<= 1) {
    const int t = (tid >= off) ? sc[tid - off] : 0;
    __syncthreads();
    sc[tid] += t;
    __syncthreads();
  }
  const int ex = base + sc[tid] - v;  // exclusive global position

  const int node = blockIdx.x * 256 + tid;
  if (node < N_NODES) rowptr[node] = ex;

  cnt[tid] = ex;  // reuse as cursor
  __syncthreads();
  for (int i = base + tid; i < limit; i += 256) {
    const unsigned p = pairs[i];
    const int pos = atomicAdd(&cnt[p & 255u], 1);
    srcs[pos] = (int)(p >> 8);
  }
}

// ---------------------------------------------------------------------------
// Cast x (f32) -> xb (bf16). 8 elems/thread.
// ---------------------------------------------------------------------------
__global__ __launch_bounds__(256) void cast_x_kernel(
    const float* __restrict__ x, unsigned short* __restrict__ xb) {
  const int t = blockIdx.x * blockDim.x + threadIdx.x;
  if (t >= (N_NODES * IN_CH) / 8) return;
  const float4 a = reinterpret_cast<const float4*>(x)[t * 2];
  const float4 c = reinterpret_cast<const float4*>(x)[t * 2 + 1];
  union { unsigned int u[4]; uint4 v; } o;
  o.u[0] = (unsigned)f2bf(a.x) | ((unsigned)f2bf(a.y) << 16);
  o.u[1] = (unsigned)f2bf(a.z) | ((unsigned)f2bf(a.w) << 16);
  o.u[2] = (unsigned)f2bf(c.x) | ((unsigned)f2bf(c.y) << 16);
  o.u[3] = (unsigned)f2bf(c.z) | ((unsigned)f2bf(c.w) << 16);
  reinterpret_cast<uint4*>(xb)[t] = o.v;
}

// ---------------------------------------------------------------------------
// W [OUT_CH, FEAT] f32 -> Wf bf16 in MFMA-fragment order:
// Wf[((kk*8+nt)*64 + lane)*8 + j] = W[nt*16+(lane&15)][kk*32+(lane>>4)*8+j]
// ---------------------------------------------------------------------------
__global__ __launch_bounds__(256) void wfrag_kernel(
    const float* __restrict__ W, unsigned short* __restrict__ Wf) {
  const int t = blockIdx.x * blockDim.x + threadIdx.x;
  if (t >= 6 * 8 * 64 * 8) return;  // 24576 == FEAT*OUT_CH
  const int j = t & 7;
  const int l = (t >> 3) & 63;
  const int nt = (t >> 9) & 7;
  const int kk = t >> 12;
  const int o = nt * 16 + (l & 15);
  const int k = kk * 32 + (l >> 4) * 8 + j;
  Wf[t] = f2bf(W[o * FEAT + k]);
}

// ---------------------------------------------------------------------------
// Gather hop (bf16): hout[n][c] = sum over in-edges(n) of hin[src][c].
// One wave per node; g=lane>>3 edge slot (8 in flight), s=lane&7 channel
// slice (uint4 = 16B). f32 accumulate, shfl_xor combine.
// ---------------------------------------------------------------------------
__global__ __launch_bounds__(256) void gather_kernel(
    const unsigned short* __restrict__ hin, const int* __restrict__ rowptr,
    const int* __restrict__ srcs, unsigned short* __restrict__ hout) {
  const int gid = blockIdx.x * blockDim.x + threadIdx.x;
  const int node = gid >> 6;
  if (node >= N_NODES) return;
  const int lane = threadIdx.x & 63;
  const int g = lane >> 3;
  const int s = lane & 7;

  const int beg = rowptr[node];
  const int end = rowptr[node + 1];

  float acc[8];
#pragma unroll
  for (int j = 0; j < 8; ++j) acc[j] = 0.0f;

  for (int i = beg + g; i < end; i += 8) {
    const int src = srcs[i];
    const uint4 v = *reinterpret_cast<const uint4*>(
        hin + (size_t)src * IN_CH + s * 8);
    acc[0] += bf2f(v.x & 0xffffu); acc[1] += bf2f(v.x >> 16);
    acc[2] += bf2f(v.y & 0xffffu); acc[3] += bf2f(v.y >> 16);
    acc[4] += bf2f(v.z & 0xffffu); acc[5] += bf2f(v.z >> 16);
    acc[6] += bf2f(v.w & 0xffffu); acc[7] += bf2f(v.w >> 16);
  }

#pragma unroll
  for (int j = 0; j < 8; ++j) {
    acc[j] += __shfl_xor(acc[j], 8);
    acc[j] += __shfl_xor(acc[j], 16);
    acc[j] += __shfl_xor(acc[j], 32);
  }

  if (g == 0) {
    union { unsigned int u[4]; uint4 v; } o;
    o.u[0] = (unsigned)f2bf(acc[0]) | ((unsigned)f2bf(acc[1]) << 16);
    o.u[1] = (unsigned)f2bf(acc[2]) | ((unsigned)f2bf(acc[3]) << 16);
    o.u[2] = (unsigned)f2bf(acc[4]) | ((unsigned)f2bf(acc[5]) << 16);
    o.u[3] = (unsigned)f2bf(acc[6]) | ((unsigned)f2bf(acc[7]) << 16);
    *reinterpret_cast<uint4*>(hout + (size_t)node * IN_CH + s * 8) = o.v;
  }
}

// ---------------------------------------------------------------------------
// MFMA GEMM: out[n,o] = b[o] + [xb|h1b|h2b][n,:] @ W[o,:]  (bf16 in, f32 acc)
// One wave per 16-node tile; 8 n-tiles of 16 out-ch; K = 6 chunks of 32.
// C/D (m89-verified): D[(l>>4)*4+r][l&15].
// ---------------------------------------------------------------------------
__global__ __launch_bounds__(256) void gemm_kernel(
    const unsigned short* __restrict__ xb,
    const unsigned short* __restrict__ h1b,
    const unsigned short* __restrict__ h2b,
    const unsigned short* __restrict__ Wf, const float* __restrict__ b,
    float* __restrict__ out) {
  const int wave = (blockIdx.x * 256 + threadIdx.x) >> 6;
  if (wave >= N_TILES) return;
  const int lane = threadIdx.x & 63;
  const int node0 = wave * 16;
  const int mrow = lane & 15;
  const int kg = lane >> 4;

  f32x4 acc[8];
#pragma unroll
  for (int nt = 0; nt < 8; ++nt) acc[nt] = (f32x4){0.f, 0.f, 0.f, 0.f};

  const unsigned short* const srcarr[3] = {xb, h1b, h2b};
#pragma unroll
  for (int kk = 0; kk < 6; ++kk) {
    const unsigned short* a = srcarr[kk >> 1];
    const short8 af = *reinterpret_cast<const short8*>(
        a + (size_t)(node0 + mrow) * IN_CH + (kk & 1) * 32 + kg * 8);
#pragma unroll
    for (int nt = 0; nt < 8; ++nt) {
      const short8 bf = *reinterpret_cast<const short8*>(
          Wf + ((size_t)(kk * 8 + nt) * 64 + lane) * 8);
      acc[nt] = __builtin_amdgcn_mfma_f32_16x16x32_bf16(af, bf, acc[nt], 0, 0, 0);
    }
  }

#pragma unroll
  for (int nt = 0; nt < 8; ++nt) {
    const int oc = nt * 16 + mrow;
    const float bias = b[oc];
#pragma unroll
    for (int r = 0; r < 4; ++r) {
      out[(size_t)(node0 + kg * 4 + r) * OUT_CH + oc] = acc[nt][r] + bias;
    }
  }
}

extern "C" void kernel_launch(void* const* d_in, const int* in_sizes, int n_in,
                              void* d_out, int out_size, void* d_ws,
                              size_t ws_size, hipStream_t stream) {
  const float* x = (const float*)d_in[0];
  const int* ei = (const int*)d_in[1];   // [2, N_EDGES], int32 per harness
  const float* W = (const float*)d_in[2];
  const float* b = (const float*)d_in[3];
  float* out = (float*)d_out;

  // Workspace layout:
  //   xb | h1b | h2b (pairs aliases h2b — dead until gather hop 2) |
  //   Wf | total | boffset | rowptr | srcs (hist+offs_t alias srcs:
  //   hist dead after P2a, offs_t dead after P3, srcs written in P4).
  char* p = (char*)d_ws;
  unsigned short* xb = (unsigned short*)p;  p += (size_t)N_NODES * IN_CH * 2;
  unsigned short* h1b = (unsigned short*)p; p += (size_t)N_NODES * IN_CH * 2;
  unsigned short* h2b = (unsigned short*)p;
  unsigned* pairs = (unsigned*)h2b;         p += (size_t)N_NODES * IN_CH * 2;
  unsigned short* Wf = (unsigned short*)p;  p += (size_t)FEAT * OUT_CH * 2;
  int* total = (int*)p;   p += (size_t)NB * 4;
  int* boffset = (int*)p; p += (size_t)(NB + 1) * 4;
  int* rowptr = (int*)p;  p += (size_t)(N_NODES + 1) * 4;
  int* srcs = (int*)p;    p += (size_t)N_EDGES * 4;
  int* hist = (int*)p;    p += (size_t)NPB * NB * 4;
  int* offs_t = (int*)p;

  // Deterministic two-level partition (no global atomics, no memset).
  part_hist_kernel<<<NPB, 256, 0, stream>>>(ei, hist);
  part_scan_kernel<<<NB, 256, 0, stream>>>(hist, offs_t, total);
  part_scan2_kernel<<<1, 256, 0, stream>>>(total, boffset, rowptr);
  part_fill_kernel<<<NPB, 256, 0, stream>>>(ei, boffset, offs_t, pairs);
  bucket_csr_kernel<<<NB, 256, 0, stream>>>(pairs, boffset, rowptr, srcs);

  // bf16 casts / weight fragment shuffle.
  cast_x_kernel<<<(N_NODES * IN_CH / 8 + 255) / 256, 256, 0, stream>>>(x, xb);
  wfrag_kernel<<<(FEAT * OUT_CH + 255) / 256, 256, 0, stream>>>(W, Wf);

  // Hop 1: h1 = gather(xb); Hop 2: h2 = gather(h1b) (overwrites pairs, OK).
  const int gblocks = (N_NODES * 64 + 255) / 256;
  gather_kernel<<<gblocks, 256, 0, stream>>>(xb, rowptr, srcs, h1b);
  gather_kernel<<<gblocks, 256, 0, stream>>>(h1b, rowptr, srcs, h2b);

  // out = [xb|h1b|h2b] @ W.T + b via MFMA.
  const int gemmblocks = (N_TILES + 3) / 4;  // 4 waves per block
  gemm_kernel<<<gemmblocks, 256, 0, stream>>>(xb, h1b, h2b, Wf, b, out);
}